// Round 8
// baseline (606.736 us; speedup 1.0000x reference)
//
#include <hip/hip_runtime.h>
#include <hip/hip_bf16.h>

// TAGConv K=2, D=128. Round 8: XCD-sliced SpMM.
// h stored in 8 column-slices: hs[(slice*N + node)*8 + c] (uints, 32 B per
// node per slice). SpMM blocks bind slice = blockIdx & 7 -> each XCD's
// gathers hit only its own 3.2 MB slice (L2-resident). Per-hop HBM fetch
// drops ~183 -> ~100 MB and gathers become L2-hits.
// spmm1 also emits h1p = norm^2 * sum so spmm2 needs no per-edge norm load.
// GEMM A-frags / prescale adapted to sliced layout (16B frag reads stay
// within a 16-col slice). Build pipeline (mega + bucket_csr) unchanged.

#define D 128
#define TPB 256
#define GEMM_GRID 768

#define BSH 9
#define BSZ 512              // nodes per bucket
#define NBMAX 256            // max buckets
#define EPT 16               // edges per thread in binscatter
#define CH (TPB * EPT)       // 4096 edges per WG
#define LCAP 16384           // fixed per-bucket region (avg fill ~8.2K, ~90 sigma)

typedef __attribute__((ext_vector_type(8))) short short8;
typedef __attribute__((ext_vector_type(4))) float f32x4;

__device__ __forceinline__ ushort f2bf(float f) {
    unsigned u = __float_as_uint(f);
    u += 0x7fff + ((u >> 16) & 1);      // round-to-nearest-even
    return (ushort)(u >> 16);
}
__device__ __forceinline__ unsigned pack2bf(float x, float y) {
    return (unsigned)f2bf(x) | ((unsigned)f2bf(y) << 16);
}
__device__ __forceinline__ float bf_lo(unsigned v) { return __uint_as_float(v << 16); }
__device__ __forceinline__ float bf_hi(unsigned v) { return __uint_as_float(v & 0xffff0000u); }

// ---------------- mega: binscatter || prescale(sliced) || wconv ----------------
__global__ __launch_bounds__(TPB) void mega_kernel(
    const int* __restrict__ src, const int* __restrict__ dst,
    int* __restrict__ gCursor, unsigned* __restrict__ tmp,
    const float* __restrict__ feat, unsigned* __restrict__ featb,
    const float* __restrict__ W, ushort* __restrict__ Wb,
    int e, int n, int nbin, int npre) {
    __shared__ int hist[NBMAX];
    __shared__ int cellBase[NBMAX];
    int t = threadIdx.x;
    int bid = blockIdx.x;

    if (bid < nbin) {
        hist[t] = 0;
        __syncthreads();
        int base = bid * CH;
        int b[EPT]; unsigned pk[EPT]; int r[EPT];
#pragma unroll
        for (int k = 0; k < EPT; ++k) {
            int i = base + k * TPB + t;
            b[k] = -1;
            if (i < e) {
                int d = dst[i];
                b[k] = d >> BSH;
                pk[k] = ((unsigned)src[i] << BSH) | (unsigned)(d & (BSZ - 1));
                r[k] = atomicAdd(&hist[b[k]], 1);
            }
        }
        __syncthreads();
        int h = hist[t];
        cellBase[t] = h ? t * LCAP + atomicAdd(&gCursor[t], h) : 0;
        __syncthreads();
#pragma unroll
        for (int k = 0; k < EPT; ++k)
            if (b[k] >= 0) tmp[cellBase[b[k]] + r[k]] = pk[k];
    } else if (bid < nbin + npre) {
        int gid = (bid - nbin) * TPB + t;
        int node = gid >> 6, c = gid & 63;        // c = float2 index (cols 2c,2c+1)
        if (node >= n) return;
        float2 f = ((const float2*)feat)[(size_t)node * 64 + c];
        int sl = c >> 3, cc = c & 7;              // slice = 2c/16, uint offset
        featb[((size_t)sl * n + node) * 8 + cc] = pack2bf(f.x, f.y);
    } else {
        int i = ((bid - nbin - npre) * TPB + t) * 4;   // D*384 = 49152 elems
        float4 w = *(const float4*)(W + i);
        ushort4 o;
        o.x = f2bf(w.x); o.y = f2bf(w.y); o.z = f2bf(w.z); o.w = f2bf(w.w);
        *(ushort4*)(Wb + i) = o;
    }
}

// ---------------- per-bucket CSR in LDS + sequential dump ----------
__global__ __launch_bounds__(TPB) void bucket_csr_kernel(
    const unsigned* __restrict__ tmp, const int* __restrict__ gCursor,
    int2* __restrict__ rsdeg, float* __restrict__ norm, int* __restrict__ csr,
    int n) {
    __shared__ int cnt[BSZ];
    __shared__ int off[BSZ];
    __shared__ int pr[TPB];
    __shared__ int lcsr[LCAP];
    int t = threadIdx.x;
    int bkt = blockIdx.x;
    int beg = bkt * LCAP;
    int m = gCursor[bkt];
    int end = beg + m;
    cnt[t] = 0; cnt[t + TPB] = 0;
    __syncthreads();
    for (int i = beg + t; i < end; i += TPB)
        atomicAdd(&cnt[tmp[i] & (BSZ - 1)], 1);
    __syncthreads();
    int c0 = cnt[2 * t], c1 = cnt[2 * t + 1];
    int own = c0 + c1;
    pr[t] = own;
    __syncthreads();
    for (int o = 1; o < TPB; o <<= 1) {
        int x = (t >= o) ? pr[t - o] : 0;
        __syncthreads();
        pr[t] += x;
        __syncthreads();
    }
    int ex = pr[t] - own;
    off[2 * t] = ex;
    off[2 * t + 1] = ex + c0;
    __syncthreads();
    cnt[t] = 0; cnt[t + TPB] = 0;          // reuse as rank counters
    __syncthreads();
    for (int i = beg + t; i < end; i += TPB) {
        unsigned v = tmp[i];
        int l = v & (BSZ - 1);
        int r = atomicAdd(&cnt[l], 1);
        int idx = off[l] + r;
        if (idx < LCAP) lcsr[idx] = (int)(v >> BSH);
    }
    __syncthreads();
    int mm = m < LCAP ? m : LCAP;
    for (int i = t; i < mm; i += TPB) csr[beg + i] = lcsr[i];   // sequential
    int node0 = bkt << BSH;
    for (int l = t; l < BSZ; l += TPB) {
        int node = node0 + l;
        if (node < n) {
            rsdeg[node] = make_int2(beg + off[l], cnt[l]);
            norm[node] = rsqrtf((float)cnt[l]);
        }
    }
}

// ---------------- SpMM hop 1 (sliced): block slice = blockIdx&7 ----------------
// Wave per node: e=lane>>3 -> 8 edges in flight, c=lane&7 -> 32B slice row.
// Emits h1b = nv*sum (GEMM input) and h1p = nv^2*sum (hop-2 input).
__global__ __launch_bounds__(TPB) void spmm1_kernel(
    const unsigned* __restrict__ featb, const int2* __restrict__ rsdeg,
    const int* __restrict__ csr, const float* __restrict__ norm,
    unsigned* __restrict__ h1b, unsigned* __restrict__ h1p, int n) {
    int wave = threadIdx.x >> 6, lane = threadIdx.x & 63;
    int slice = blockIdx.x & 7;
    int v = (blockIdx.x >> 3) * 4 + wave;
    if (v >= n) return;
    int e = lane >> 3, c = lane & 7;
    int2 rd = rsdeg[v];
    int beg = rd.x, end = rd.x + rd.y;
    const unsigned* hs = featb + (size_t)slice * n * 8;
    float ax = 0.f, ay = 0.f;
#pragma unroll 2
    for (int j = beg + e; j < end; j += 8) {
        int u = csr[j];
        float s = norm[u];
        unsigned hv = hs[u * 8 + c];
        ax = fmaf(s, bf_lo(hv), ax);
        ay = fmaf(s, bf_hi(hv), ay);
    }
#pragma unroll
    for (int o = 8; o < 64; o <<= 1) {
        ax += __shfl_xor(ax, o, 64);
        ay += __shfl_xor(ay, o, 64);
    }
    if (e == 0) {
        float nv = norm[v];
        size_t idx = ((size_t)slice * n + v) * 8 + c;
        h1b[idx] = pack2bf(ax * nv, ay * nv);
        float n2 = nv * nv;
        h1p[idx] = pack2bf(ax * n2, ay * n2);
    }
}

// ---------------- SpMM hop 2 (sliced): input pre-scaled, no norm gather ------
__global__ __launch_bounds__(TPB) void spmm2_kernel(
    const unsigned* __restrict__ h1p, const int2* __restrict__ rsdeg,
    const int* __restrict__ csr, const float* __restrict__ norm,
    unsigned* __restrict__ h2b, int n) {
    int wave = threadIdx.x >> 6, lane = threadIdx.x & 63;
    int slice = blockIdx.x & 7;
    int v = (blockIdx.x >> 3) * 4 + wave;
    if (v >= n) return;
    int e = lane >> 3, c = lane & 7;
    int2 rd = rsdeg[v];
    int beg = rd.x, end = rd.x + rd.y;
    const unsigned* hs = h1p + (size_t)slice * n * 8;
    float ax = 0.f, ay = 0.f;
#pragma unroll 2
    for (int j = beg + e; j < end; j += 8) {
        int u = csr[j];
        unsigned hv = hs[u * 8 + c];
        ax += bf_lo(hv);
        ay += bf_hi(hv);
    }
#pragma unroll
    for (int o = 8; o < 64; o <<= 1) {
        ax += __shfl_xor(ax, o, 64);
        ay += __shfl_xor(ay, o, 64);
    }
    if (e == 0) {
        float nv = norm[v];
        h2b[((size_t)slice * n + v) * 8 + c] = pack2bf(ax * nv, ay * nv);
    }
}

// ---------------- GEMM: out[n][128] = [featb|h1b|h2b] @ Wb^T + b --------------
// A arrays are in sliced layout; each 16B frag read stays within one slice.
__global__ __launch_bounds__(TPB) void gemm_mfma_kernel(
    const ushort* __restrict__ featb, const ushort* __restrict__ h1b,
    const ushort* __restrict__ h2b, const ushort* __restrict__ Wb,
    const float* __restrict__ bias, float* __restrict__ out, int n, int ntiles) {
    int lane = threadIdx.x & 63;
    int wave = threadIdx.x >> 6;
    int m = lane & 15, q = lane >> 4;

    short8 b[12][2];
#pragma unroll
    for (int ks = 0; ks < 12; ++ks)
#pragma unroll
        for (int t = 0; t < 2; ++t)
            b[ks][t] = *(const short8*)(Wb + (size_t)(wave * 32 + t * 16 + m) * 384
                                        + ks * 32 + q * 8);
    float bv0 = bias[wave * 32 + m];
    float bv1 = bias[wave * 32 + 16 + m];

    const ushort* srcs[3] = {featb, h1b, h2b};

    for (int tile = blockIdx.x; tile < ntiles; tile += gridDim.x) {
        int row = tile * 16 + m;
        bool va = row < n;
        short8 a[12] = {};
        if (va) {
#pragma unroll
            for (int ks = 0; ks < 12; ++ks) {
                int col0 = (ks & 3) * 32 + q * 8;
                int sl = col0 >> 4, o = col0 & 15;
                a[ks] = *(const short8*)(srcs[ks >> 2]
                                         + ((size_t)sl * n + row) * 16 + o);
            }
        }
        f32x4 acc0 = {}, acc1 = {};
#pragma unroll
        for (int ks = 0; ks < 12; ++ks) {
            acc0 = __builtin_amdgcn_mfma_f32_16x16x32_bf16(a[ks], b[ks][0], acc0, 0, 0, 0);
            acc1 = __builtin_amdgcn_mfma_f32_16x16x32_bf16(a[ks], b[ks][1], acc1, 0, 0, 0);
        }
        int r0 = tile * 16 + q * 4;
#pragma unroll
        for (int r = 0; r < 4; ++r) {
            int rw = r0 + r;
            if (rw < n) {
                size_t o = (size_t)rw * D + wave * 32 + m;
                out[o] = acc0[r] + bv0;
                out[o + 16] = acc1[r] + bv1;
            }
        }
    }
}

extern "C" void kernel_launch(void* const* d_in, const int* in_sizes, int n_in,
                              void* d_out, int out_size, void* d_ws, size_t ws_size,
                              hipStream_t stream) {
    const float* feat = (const float*)d_in[0];
    const int* src    = (const int*)d_in[1];
    const int* dst    = (const int*)d_in[2];
    const float* W    = (const float*)d_in[3];
    const float* bias = (const float*)d_in[4];
    float* out        = (float*)d_out;

    const int N = in_sizes[0] / D;        // 100000
    const int E = in_sizes[1];            // 1600000
    const int NB = (N + BSZ - 1) >> BSH;  // 196

    char* ws = (char*)d_ws;
    size_t off = 0;
    auto bump = [&](size_t bytes) {
        char* p = ws + off;
        off += (bytes + 255) & ~(size_t)255;
        return p;
    };
    int* gCursor     = (int*)bump((size_t)NBMAX * 4);            // memset to 0
    float* norm      = (float*)bump((size_t)N * 4);
    int2* rsdeg      = (int2*)bump((size_t)N * 8);
    unsigned* tmp    = (unsigned*)bump((size_t)NB * LCAP * 4);   // 12.85 MB
    int* csr         = (int*)bump((size_t)NB * LCAP * 4);        // 12.85 MB
    unsigned* featb  = (unsigned*)bump((size_t)N * 64 * 4);      // sliced bf16x2
    unsigned* h1b    = (unsigned*)bump((size_t)N * 64 * 4);
    unsigned* h1p    = (unsigned*)bump((size_t)N * 64 * 4);
    unsigned* h2b    = (unsigned*)bump((size_t)N * 64 * 4);
    ushort* Wb       = (ushort*)bump((size_t)D * 384 * 2);
    (void)ws_size;

    hipMemsetAsync(gCursor, 0, (size_t)NBMAX * 4, stream);

    const int nbin = (E + CH - 1) / CH;                // 391
    const int npre = (N * 64 + TPB - 1) / TPB;         // 25000
    const int nwcv = (D * 384 / 4 + TPB - 1) / TPB;    // 48
    mega_kernel<<<nbin + npre + nwcv, TPB, 0, stream>>>(
        src, dst, gCursor, tmp, feat, featb, W, Wb, E, N, nbin, npre);

    bucket_csr_kernel<<<NB, TPB, 0, stream>>>(tmp, gCursor, rsdeg, norm, csr, N);

    const int nsp = ((N + 3) / 4) * 8;                 // 200000 blocks
    spmm1_kernel<<<nsp, TPB, 0, stream>>>(featb, rsdeg, csr, norm, h1b, h1p, N);
    spmm2_kernel<<<nsp, TPB, 0, stream>>>(h1p, rsdeg, csr, norm, h2b, N);

    const int ntiles = (N + 15) / 16;                  // 6250
    gemm_mfma_kernel<<<GEMM_GRID, TPB, 0, stream>>>(
        (const ushort*)featb, (const ushort*)h1b, (const ushort*)h2b,
        Wb, bias, out, N, ntiles);
}

// Round 9
// 313.032 us; speedup vs baseline: 1.9383x; 1.9383x over previous
//
#include <hip/hip_runtime.h>
#include <hip/hip_bf16.h>

// TAGConv K=2, D=128. Round 9: revert round-8 slicing (failed: fetch dropped
// 183->72 MB but dur 4x worse -> spmm is latency/VMEM-queue-bound, NOT
// fetch-bound; 8x wave count + 4x gather instructions killed it).
// Back to round-7 structure (wave-per-node, 1KB gathers, unroll 4), plus:
//   spmm1 emits h1p = norm^2 * sum  ->  spmm2 loop has NO per-edge norm load
//   (2 VMEM/iter instead of 3, shorter csr->gather chain).

#define D 128
#define TPB 256
#define GEMM_GRID 768

#define BSH 9
#define BSZ 512              // nodes per bucket
#define NBMAX 256            // max buckets
#define EPT 16               // edges per thread in binscatter
#define CH (TPB * EPT)       // 4096 edges per WG
#define LCAP 16384           // fixed per-bucket region (avg fill ~8.2K, ~90 sigma)

typedef __attribute__((ext_vector_type(8))) short short8;
typedef __attribute__((ext_vector_type(4))) float f32x4;

__device__ __forceinline__ ushort f2bf(float f) {
    unsigned u = __float_as_uint(f);
    u += 0x7fff + ((u >> 16) & 1);      // round-to-nearest-even
    return (ushort)(u >> 16);
}
__device__ __forceinline__ unsigned pack2bf(float x, float y) {
    return (unsigned)f2bf(x) | ((unsigned)f2bf(y) << 16);
}
__device__ __forceinline__ float bf_lo(unsigned v) { return __uint_as_float(v << 16); }
__device__ __forceinline__ float bf_hi(unsigned v) { return __uint_as_float(v & 0xffff0000u); }

// ---------------- mega: binscatter || prescale || wconv ----------------
__global__ __launch_bounds__(TPB) void mega_kernel(
    const int* __restrict__ src, const int* __restrict__ dst,
    int* __restrict__ gCursor, unsigned* __restrict__ tmp,
    const float* __restrict__ feat, unsigned* __restrict__ featb,
    const float* __restrict__ W, ushort* __restrict__ Wb,
    int e, int n, int nbin, int npre) {
    __shared__ int hist[NBMAX];
    __shared__ int cellBase[NBMAX];
    int t = threadIdx.x;
    int bid = blockIdx.x;

    if (bid < nbin) {
        hist[t] = 0;
        __syncthreads();
        int base = bid * CH;
        int b[EPT]; unsigned pk[EPT]; int r[EPT];
#pragma unroll
        for (int k = 0; k < EPT; ++k) {
            int i = base + k * TPB + t;
            b[k] = -1;
            if (i < e) {
                int d = dst[i];
                b[k] = d >> BSH;
                pk[k] = ((unsigned)src[i] << BSH) | (unsigned)(d & (BSZ - 1));
                r[k] = atomicAdd(&hist[b[k]], 1);
            }
        }
        __syncthreads();
        int h = hist[t];
        cellBase[t] = h ? t * LCAP + atomicAdd(&gCursor[t], h) : 0;
        __syncthreads();
#pragma unroll
        for (int k = 0; k < EPT; ++k)
            if (b[k] >= 0) tmp[cellBase[b[k]] + r[k]] = pk[k];
    } else if (bid < nbin + npre) {
        int gid = (bid - nbin) * TPB + t;
        int node = gid >> 6, c = gid & 63;
        if (node >= n) return;
        float2 f = ((const float2*)feat)[(size_t)node * 64 + c];
        featb[(size_t)node * 64 + c] = pack2bf(f.x, f.y);
    } else {
        int i = ((bid - nbin - npre) * TPB + t) * 4;   // D*384 = 49152 elems
        float4 w = *(const float4*)(W + i);
        ushort4 o;
        o.x = f2bf(w.x); o.y = f2bf(w.y); o.z = f2bf(w.z); o.w = f2bf(w.w);
        *(ushort4*)(Wb + i) = o;
    }
}

// ---------------- per-bucket CSR in LDS + sequential dump ----------
__global__ __launch_bounds__(TPB) void bucket_csr_kernel(
    const unsigned* __restrict__ tmp, const int* __restrict__ gCursor,
    int2* __restrict__ rsdeg, float* __restrict__ norm, int* __restrict__ csr,
    int n) {
    __shared__ int cnt[BSZ];
    __shared__ int off[BSZ];
    __shared__ int pr[TPB];
    __shared__ int lcsr[LCAP];
    int t = threadIdx.x;
    int bkt = blockIdx.x;
    int beg = bkt * LCAP;
    int m = gCursor[bkt];
    int end = beg + m;
    cnt[t] = 0; cnt[t + TPB] = 0;
    __syncthreads();
    for (int i = beg + t; i < end; i += TPB)
        atomicAdd(&cnt[tmp[i] & (BSZ - 1)], 1);
    __syncthreads();
    int c0 = cnt[2 * t], c1 = cnt[2 * t + 1];
    int own = c0 + c1;
    pr[t] = own;
    __syncthreads();
    for (int o = 1; o < TPB; o <<= 1) {
        int x = (t >= o) ? pr[t - o] : 0;
        __syncthreads();
        pr[t] += x;
        __syncthreads();
    }
    int ex = pr[t] - own;
    off[2 * t] = ex;
    off[2 * t + 1] = ex + c0;
    __syncthreads();
    cnt[t] = 0; cnt[t + TPB] = 0;          // reuse as rank counters
    __syncthreads();
    for (int i = beg + t; i < end; i += TPB) {
        unsigned v = tmp[i];
        int l = v & (BSZ - 1);
        int r = atomicAdd(&cnt[l], 1);
        int idx = off[l] + r;
        if (idx < LCAP) lcsr[idx] = (int)(v >> BSH);
    }
    __syncthreads();
    int mm = m < LCAP ? m : LCAP;
    for (int i = t; i < mm; i += TPB) csr[beg + i] = lcsr[i];   // sequential
    int node0 = bkt << BSH;
    for (int l = t; l < BSZ; l += TPB) {
        int node = node0 + l;
        if (node < n) {
            rsdeg[node] = make_int2(beg + off[l], cnt[l]);
            norm[node] = rsqrtf((float)cnt[l]);
        }
    }
}

// ---------------- SpMM hop 1: gather + per-edge norm; emits h1b and h1p -----
// One wave per dst node; quarter-wave q handles edge beg+j*4+q; c = lane&15
// handles a 16B column chunk. 1 KB per gather instruction; unroll 4.
// h1b = nv*S (GEMM input), h1p = nv^2*S (pre-scaled hop-2 input).
__global__ __launch_bounds__(TPB) void spmm1_kernel(
    const uint4* __restrict__ hin4, const int2* __restrict__ rsdeg,
    const int* __restrict__ csr, const float* __restrict__ norm,
    unsigned* __restrict__ h1b, unsigned* __restrict__ h1p, int n) {
    int w = (blockIdx.x * TPB + threadIdx.x) >> 6;
    if (w >= n) return;
    int lane = threadIdx.x & 63;
    int q = lane >> 4;
    int c = lane & 15;
    int2 rd = rsdeg[w];
    int beg = rd.x, end = rd.x + rd.y;
    float acc[8] = {};
#pragma unroll 4
    for (int j = beg + q; j < end; j += 4) {
        int u = csr[j];
        float s = norm[u];
        uint4 v = hin4[(u << 4) + c];
        acc[0] = fmaf(s, bf_lo(v.x), acc[0]);
        acc[1] = fmaf(s, bf_hi(v.x), acc[1]);
        acc[2] = fmaf(s, bf_lo(v.y), acc[2]);
        acc[3] = fmaf(s, bf_hi(v.y), acc[3]);
        acc[4] = fmaf(s, bf_lo(v.z), acc[4]);
        acc[5] = fmaf(s, bf_hi(v.z), acc[5]);
        acc[6] = fmaf(s, bf_lo(v.w), acc[6]);
        acc[7] = fmaf(s, bf_hi(v.w), acc[7]);
    }
#pragma unroll
    for (int k = 0; k < 8; ++k) {
        acc[k] += __shfl_xor(acc[k], 16, 64);
        acc[k] += __shfl_xor(acc[k], 32, 64);
    }
    if (q == 0) {
        float nv = norm[w];
        float n2 = nv * nv;
        uint4 r;
        r.x = pack2bf(acc[0] * nv, acc[1] * nv);
        r.y = pack2bf(acc[2] * nv, acc[3] * nv);
        r.z = pack2bf(acc[4] * nv, acc[5] * nv);
        r.w = pack2bf(acc[6] * nv, acc[7] * nv);
        *(uint4*)(h1b + (size_t)w * 64 + c * 4) = r;
        uint4 p;
        p.x = pack2bf(acc[0] * n2, acc[1] * n2);
        p.y = pack2bf(acc[2] * n2, acc[3] * n2);
        p.z = pack2bf(acc[4] * n2, acc[5] * n2);
        p.w = pack2bf(acc[6] * n2, acc[7] * n2);
        *(uint4*)(h1p + (size_t)w * 64 + c * 4) = p;
    }
}

// ---------------- SpMM hop 2: input pre-scaled -> 2 VMEM/iter, adds only ----
__global__ __launch_bounds__(TPB) void spmm2_kernel(
    const uint4* __restrict__ hin4, const int2* __restrict__ rsdeg,
    const int* __restrict__ csr, const float* __restrict__ norm,
    unsigned* __restrict__ hout, int n) {
    int w = (blockIdx.x * TPB + threadIdx.x) >> 6;
    if (w >= n) return;
    int lane = threadIdx.x & 63;
    int q = lane >> 4;
    int c = lane & 15;
    int2 rd = rsdeg[w];
    int beg = rd.x, end = rd.x + rd.y;
    float acc[8] = {};
#pragma unroll 4
    for (int j = beg + q; j < end; j += 4) {
        int u = csr[j];
        uint4 v = hin4[(u << 4) + c];
        acc[0] += bf_lo(v.x);
        acc[1] += bf_hi(v.x);
        acc[2] += bf_lo(v.y);
        acc[3] += bf_hi(v.y);
        acc[4] += bf_lo(v.z);
        acc[5] += bf_hi(v.z);
        acc[6] += bf_lo(v.w);
        acc[7] += bf_hi(v.w);
    }
#pragma unroll
    for (int k = 0; k < 8; ++k) {
        acc[k] += __shfl_xor(acc[k], 16, 64);
        acc[k] += __shfl_xor(acc[k], 32, 64);
    }
    if (q == 0) {
        float nv = norm[w];
        uint4 r;
        r.x = pack2bf(acc[0] * nv, acc[1] * nv);
        r.y = pack2bf(acc[2] * nv, acc[3] * nv);
        r.z = pack2bf(acc[4] * nv, acc[5] * nv);
        r.w = pack2bf(acc[6] * nv, acc[7] * nv);
        *(uint4*)(hout + (size_t)w * 64 + c * 4) = r;
    }
}

// ---------------- GEMM: out[n][128] = [featb|h1b|h2b] @ Wb^T + b --------------
// 4 waves/block; wave owns a 32-col W slice in registers (24 bf16 frags).
// A frag: row m=lane&15, k=(lane>>4)*8+j.  C/D: col=lane&15, row=(lane>>4)*4+reg.
__global__ __launch_bounds__(TPB) void gemm_mfma_kernel(
    const ushort* __restrict__ featb, const ushort* __restrict__ h1b,
    const ushort* __restrict__ h2b, const ushort* __restrict__ Wb,
    const float* __restrict__ bias, float* __restrict__ out, int n, int ntiles) {
    int lane = threadIdx.x & 63;
    int wave = threadIdx.x >> 6;
    int m = lane & 15, q = lane >> 4;

    short8 b[12][2];
#pragma unroll
    for (int ks = 0; ks < 12; ++ks)
#pragma unroll
        for (int t = 0; t < 2; ++t)
            b[ks][t] = *(const short8*)(Wb + (size_t)(wave * 32 + t * 16 + m) * 384
                                        + ks * 32 + q * 8);
    float bv0 = bias[wave * 32 + m];
    float bv1 = bias[wave * 32 + 16 + m];

    const ushort* srcs[3] = {featb, h1b, h2b};

    for (int tile = blockIdx.x; tile < ntiles; tile += gridDim.x) {
        int row = tile * 16 + m;
        bool va = row < n;
        size_t arow = (size_t)row * D;
        short8 a[12] = {};
        if (va) {
#pragma unroll
            for (int ks = 0; ks < 12; ++ks)
                a[ks] = *(const short8*)(srcs[ks >> 2] + arow + (ks & 3) * 32 + q * 8);
        }
        f32x4 acc0 = {}, acc1 = {};
#pragma unroll
        for (int ks = 0; ks < 12; ++ks) {
            acc0 = __builtin_amdgcn_mfma_f32_16x16x32_bf16(a[ks], b[ks][0], acc0, 0, 0, 0);
            acc1 = __builtin_amdgcn_mfma_f32_16x16x32_bf16(a[ks], b[ks][1], acc1, 0, 0, 0);
        }
        int r0 = tile * 16 + q * 4;
#pragma unroll
        for (int r = 0; r < 4; ++r) {
            int rw = r0 + r;
            if (rw < n) {
                size_t o = (size_t)rw * D + wave * 32 + m;
                out[o] = acc0[r] + bv0;
                out[o + 16] = acc1[r] + bv1;
            }
        }
    }
}

extern "C" void kernel_launch(void* const* d_in, const int* in_sizes, int n_in,
                              void* d_out, int out_size, void* d_ws, size_t ws_size,
                              hipStream_t stream) {
    const float* feat = (const float*)d_in[0];
    const int* src    = (const int*)d_in[1];
    const int* dst    = (const int*)d_in[2];
    const float* W    = (const float*)d_in[3];
    const float* bias = (const float*)d_in[4];
    float* out        = (float*)d_out;

    const int N = in_sizes[0] / D;        // 100000
    const int E = in_sizes[1];            // 1600000
    const int NB = (N + BSZ - 1) >> BSH;  // 196

    char* ws = (char*)d_ws;
    size_t off = 0;
    auto bump = [&](size_t bytes) {
        char* p = ws + off;
        off += (bytes + 255) & ~(size_t)255;
        return p;
    };
    int* gCursor     = (int*)bump((size_t)NBMAX * 4);            // memset to 0
    float* norm      = (float*)bump((size_t)N * 4);
    int2* rsdeg      = (int2*)bump((size_t)N * 8);
    unsigned* tmp    = (unsigned*)bump((size_t)NB * LCAP * 4);   // 12.85 MB
    int* csr         = (int*)bump((size_t)NB * LCAP * 4);        // 12.85 MB
    unsigned* featb  = (unsigned*)bump((size_t)N * 64 * 4);      // bf16x2 rows
    unsigned* h1b    = (unsigned*)bump((size_t)N * 64 * 4);
    unsigned* h1p    = (unsigned*)bump((size_t)N * 64 * 4);
    unsigned* h2b    = (unsigned*)bump((size_t)N * 64 * 4);
    ushort* Wb       = (ushort*)bump((size_t)D * 384 * 2);
    (void)ws_size;

    hipMemsetAsync(gCursor, 0, (size_t)NBMAX * 4, stream);

    const int nbin = (E + CH - 1) / CH;                // 391
    const int npre = (N * 64 + TPB - 1) / TPB;         // 25000
    const int nwcv = (D * 384 / 4 + TPB - 1) / TPB;    // 48
    mega_kernel<<<nbin + npre + nwcv, TPB, 0, stream>>>(
        src, dst, gCursor, tmp, feat, featb, W, Wb, E, N, nbin, npre);

    bucket_csr_kernel<<<NB, TPB, 0, stream>>>(tmp, gCursor, rsdeg, norm, csr, N);

    const int spmm_blocks = (N * 64 + TPB - 1) / TPB;  // 1 wave per node
    spmm1_kernel<<<spmm_blocks, TPB, 0, stream>>>(
        (const uint4*)featb, rsdeg, csr, norm, h1b, h1p, N);
    spmm2_kernel<<<spmm_blocks, TPB, 0, stream>>>(
        (const uint4*)h1p, rsdeg, csr, norm, h2b, N);

    const int ntiles = (N + 15) / 16;                  // 6250
    gemm_mfma_kernel<<<GEMM_GRID, TPB, 0, stream>>>(
        (const ushort*)featb, (const ushort*)h1b, (const ushort*)h2b,
        Wb, bias, out, N, ntiles);
}

// Round 10
// 308.891 us; speedup vs baseline: 1.9642x; 1.0134x over previous
//
#include <hip/hip_runtime.h>
#include <hip/hip_bf16.h>

// TAGConv K=2, D=128. Round 10:
//  - Revert round-9 h1p (spmm2's VMEM-cut gained 0; spmm1's extra write cost
//    +4 us). SpMM = round-7 proven form for both hops (62.5 us/hop = its
//    random-gather structural floor; rounds 8+9 falsified fetch- and
//    VMEM-count-reduction).
//  - GEMM: 2 tiles per grid-stride iteration. All 24 A-loads issued up
//    front; MFMA of tile-A waits vmcnt on only its 12, tile-B loads stay in
//    flight under A's MFMA+stores -> doubles per-wave MLP on the
//    latency-bound A stream. __launch_bounds__(256,2), ~220 VGPR, no spill.

#define D 128
#define TPB 256
#define GEMM_GRID 768

#define BSH 9
#define BSZ 512              // nodes per bucket
#define NBMAX 256            // max buckets
#define EPT 16               // edges per thread in binscatter
#define CH (TPB * EPT)       // 4096 edges per WG
#define LCAP 16384           // fixed per-bucket region (avg fill ~8.2K, ~90 sigma)

typedef __attribute__((ext_vector_type(8))) short short8;
typedef __attribute__((ext_vector_type(4))) float f32x4;

__device__ __forceinline__ ushort f2bf(float f) {
    unsigned u = __float_as_uint(f);
    u += 0x7fff + ((u >> 16) & 1);      // round-to-nearest-even
    return (ushort)(u >> 16);
}
__device__ __forceinline__ unsigned pack2bf(float x, float y) {
    return (unsigned)f2bf(x) | ((unsigned)f2bf(y) << 16);
}
__device__ __forceinline__ float bf_lo(unsigned v) { return __uint_as_float(v << 16); }
__device__ __forceinline__ float bf_hi(unsigned v) { return __uint_as_float(v & 0xffff0000u); }

// ---------------- mega: binscatter || prescale || wconv ----------------
__global__ __launch_bounds__(TPB) void mega_kernel(
    const int* __restrict__ src, const int* __restrict__ dst,
    int* __restrict__ gCursor, unsigned* __restrict__ tmp,
    const float* __restrict__ feat, unsigned* __restrict__ featb,
    const float* __restrict__ W, ushort* __restrict__ Wb,
    int e, int n, int nbin, int npre) {
    __shared__ int hist[NBMAX];
    __shared__ int cellBase[NBMAX];
    int t = threadIdx.x;
    int bid = blockIdx.x;

    if (bid < nbin) {
        hist[t] = 0;
        __syncthreads();
        int base = bid * CH;
        int b[EPT]; unsigned pk[EPT]; int r[EPT];
#pragma unroll
        for (int k = 0; k < EPT; ++k) {
            int i = base + k * TPB + t;
            b[k] = -1;
            if (i < e) {
                int d = dst[i];
                b[k] = d >> BSH;
                pk[k] = ((unsigned)src[i] << BSH) | (unsigned)(d & (BSZ - 1));
                r[k] = atomicAdd(&hist[b[k]], 1);
            }
        }
        __syncthreads();
        int h = hist[t];
        cellBase[t] = h ? t * LCAP + atomicAdd(&gCursor[t], h) : 0;
        __syncthreads();
#pragma unroll
        for (int k = 0; k < EPT; ++k)
            if (b[k] >= 0) tmp[cellBase[b[k]] + r[k]] = pk[k];
    } else if (bid < nbin + npre) {
        int gid = (bid - nbin) * TPB + t;
        int node = gid >> 6, c = gid & 63;
        if (node >= n) return;
        float2 f = ((const float2*)feat)[(size_t)node * 64 + c];
        featb[(size_t)node * 64 + c] = pack2bf(f.x, f.y);
    } else {
        int i = ((bid - nbin - npre) * TPB + t) * 4;   // D*384 = 49152 elems
        float4 w = *(const float4*)(W + i);
        ushort4 o;
        o.x = f2bf(w.x); o.y = f2bf(w.y); o.z = f2bf(w.z); o.w = f2bf(w.w);
        *(ushort4*)(Wb + i) = o;
    }
}

// ---------------- per-bucket CSR in LDS + sequential dump ----------
__global__ __launch_bounds__(TPB) void bucket_csr_kernel(
    const unsigned* __restrict__ tmp, const int* __restrict__ gCursor,
    int2* __restrict__ rsdeg, float* __restrict__ norm, int* __restrict__ csr,
    int n) {
    __shared__ int cnt[BSZ];
    __shared__ int off[BSZ];
    __shared__ int pr[TPB];
    __shared__ int lcsr[LCAP];
    int t = threadIdx.x;
    int bkt = blockIdx.x;
    int beg = bkt * LCAP;
    int m = gCursor[bkt];
    int end = beg + m;
    cnt[t] = 0; cnt[t + TPB] = 0;
    __syncthreads();
    for (int i = beg + t; i < end; i += TPB)
        atomicAdd(&cnt[tmp[i] & (BSZ - 1)], 1);
    __syncthreads();
    int c0 = cnt[2 * t], c1 = cnt[2 * t + 1];
    int own = c0 + c1;
    pr[t] = own;
    __syncthreads();
    for (int o = 1; o < TPB; o <<= 1) {
        int x = (t >= o) ? pr[t - o] : 0;
        __syncthreads();
        pr[t] += x;
        __syncthreads();
    }
    int ex = pr[t] - own;
    off[2 * t] = ex;
    off[2 * t + 1] = ex + c0;
    __syncthreads();
    cnt[t] = 0; cnt[t + TPB] = 0;          // reuse as rank counters
    __syncthreads();
    for (int i = beg + t; i < end; i += TPB) {
        unsigned v = tmp[i];
        int l = v & (BSZ - 1);
        int r = atomicAdd(&cnt[l], 1);
        int idx = off[l] + r;
        if (idx < LCAP) lcsr[idx] = (int)(v >> BSH);
    }
    __syncthreads();
    int mm = m < LCAP ? m : LCAP;
    for (int i = t; i < mm; i += TPB) csr[beg + i] = lcsr[i];   // sequential
    int node0 = bkt << BSH;
    for (int l = t; l < BSZ; l += TPB) {
        int node = node0 + l;
        if (node < n) {
            rsdeg[node] = make_int2(beg + off[l], cnt[l]);
            norm[node] = rsqrtf((float)cnt[l]);
        }
    }
}

// ---------------- SpMM: hout[v] = bf16( norm[v] * sum_u norm[u]*hin[u] ) ----
// One wave per dst node; quarter-wave q handles edge beg+j*4+q; c = lane&15
// handles a 16B column chunk. 1 KB per gather instruction; unroll 4.
// Round-7 proven form: 62.5 us/hop = the random-gather structural floor.
__global__ __launch_bounds__(TPB) void spmm_kernel(
    const uint4* __restrict__ hin4, const int2* __restrict__ rsdeg,
    const int* __restrict__ csr, const float* __restrict__ norm,
    unsigned* __restrict__ hout, int n) {
    int w = (blockIdx.x * TPB + threadIdx.x) >> 6;
    if (w >= n) return;
    int lane = threadIdx.x & 63;
    int q = lane >> 4;
    int c = lane & 15;
    int2 rd = rsdeg[w];
    int beg = rd.x, end = rd.x + rd.y;
    float acc[8] = {};
#pragma unroll 4
    for (int j = beg + q; j < end; j += 4) {
        int u = csr[j];
        float s = norm[u];
        uint4 v = hin4[(u << 4) + c];
        acc[0] = fmaf(s, bf_lo(v.x), acc[0]);
        acc[1] = fmaf(s, bf_hi(v.x), acc[1]);
        acc[2] = fmaf(s, bf_lo(v.y), acc[2]);
        acc[3] = fmaf(s, bf_hi(v.y), acc[3]);
        acc[4] = fmaf(s, bf_lo(v.z), acc[4]);
        acc[5] = fmaf(s, bf_hi(v.z), acc[5]);
        acc[6] = fmaf(s, bf_lo(v.w), acc[6]);
        acc[7] = fmaf(s, bf_hi(v.w), acc[7]);
    }
#pragma unroll
    for (int k = 0; k < 8; ++k) {
        acc[k] += __shfl_xor(acc[k], 16, 64);
        acc[k] += __shfl_xor(acc[k], 32, 64);
    }
    if (q == 0) {
        float nv = norm[w];
        uint4 r;
        r.x = pack2bf(acc[0] * nv, acc[1] * nv);
        r.y = pack2bf(acc[2] * nv, acc[3] * nv);
        r.z = pack2bf(acc[4] * nv, acc[5] * nv);
        r.w = pack2bf(acc[6] * nv, acc[7] * nv);
        *(uint4*)(hout + (size_t)w * 64 + c * 4) = r;
    }
}

// ---------------- GEMM: out[n][128] = [featb|h1b|h2b] @ Wb^T + b --------------
// 4 waves/block; wave owns a 32-col W slice in registers (24 bf16 frags).
// 2 tiles per iteration: 24 A-loads batched, MFMA(A) overlaps B's loads.
// A frag: row m=lane&15, k=(lane>>4)*8+j.  C/D: col=lane&15, row=(lane>>4)*4+reg.
__global__ __launch_bounds__(TPB, 2) void gemm_mfma_kernel(
    const ushort* __restrict__ featb, const ushort* __restrict__ h1b,
    const ushort* __restrict__ h2b, const ushort* __restrict__ Wb,
    const float* __restrict__ bias, float* __restrict__ out, int n, int ntiles) {
    int lane = threadIdx.x & 63;
    int wave = threadIdx.x >> 6;
    int m = lane & 15, q = lane >> 4;

    short8 b[12][2];
#pragma unroll
    for (int ks = 0; ks < 12; ++ks)
#pragma unroll
        for (int t = 0; t < 2; ++t)
            b[ks][t] = *(const short8*)(Wb + (size_t)(wave * 32 + t * 16 + m) * 384
                                        + ks * 32 + q * 8);
    float bv0 = bias[wave * 32 + m];
    float bv1 = bias[wave * 32 + 16 + m];

    const ushort* srcs[3] = {featb, h1b, h2b};
    int stride = gridDim.x;

    for (int tileA = blockIdx.x; tileA < ntiles; tileA += 2 * stride) {
        int tileB = tileA + stride;
        int rowA = tileA * 16 + m;
        int rowB = tileB * 16 + m;
        bool vA = rowA < n;
        bool vB = tileB < ntiles && rowB < n;
        size_t arowA = (size_t)rowA * D;
        size_t arowB = (size_t)rowB * D;
        short8 aA[12] = {}, aB[12] = {};
        if (vA) {
#pragma unroll
            for (int ks = 0; ks < 12; ++ks)
                aA[ks] = *(const short8*)(srcs[ks >> 2] + arowA + (ks & 3) * 32 + q * 8);
        }
        if (vB) {
#pragma unroll
            for (int ks = 0; ks < 12; ++ks)
                aB[ks] = *(const short8*)(srcs[ks >> 2] + arowB + (ks & 3) * 32 + q * 8);
        }
        f32x4 accA0 = {}, accA1 = {}, accB0 = {}, accB1 = {};
#pragma unroll
        for (int ks = 0; ks < 12; ++ks) {
            accA0 = __builtin_amdgcn_mfma_f32_16x16x32_bf16(aA[ks], b[ks][0], accA0, 0, 0, 0);
            accA1 = __builtin_amdgcn_mfma_f32_16x16x32_bf16(aA[ks], b[ks][1], accA1, 0, 0, 0);
        }
        int rA0 = tileA * 16 + q * 4;
#pragma unroll
        for (int r = 0; r < 4; ++r) {
            int rw = rA0 + r;
            if (rw < n) {
                size_t o = (size_t)rw * D + wave * 32 + m;
                out[o] = accA0[r] + bv0;
                out[o + 16] = accA1[r] + bv1;
            }
        }
#pragma unroll
        for (int ks = 0; ks < 12; ++ks) {
            accB0 = __builtin_amdgcn_mfma_f32_16x16x32_bf16(aB[ks], b[ks][0], accB0, 0, 0, 0);
            accB1 = __builtin_amdgcn_mfma_f32_16x16x32_bf16(aB[ks], b[ks][1], accB1, 0, 0, 0);
        }
        if (vB) {
            int rB0 = tileB * 16 + q * 4;
#pragma unroll
            for (int r = 0; r < 4; ++r) {
                int rw = rB0 + r;
                if (rw < n) {
                    size_t o = (size_t)rw * D + wave * 32 + m;
                    out[o] = accB0[r] + bv0;
                    out[o + 16] = accB1[r] + bv1;
                }
            }
        }
    }
}

extern "C" void kernel_launch(void* const* d_in, const int* in_sizes, int n_in,
                              void* d_out, int out_size, void* d_ws, size_t ws_size,
                              hipStream_t stream) {
    const float* feat = (const float*)d_in[0];
    const int* src    = (const int*)d_in[1];
    const int* dst    = (const int*)d_in[2];
    const float* W    = (const float*)d_in[3];
    const float* bias = (const float*)d_in[4];
    float* out        = (float*)d_out;

    const int N = in_sizes[0] / D;        // 100000
    const int E = in_sizes[1];            // 1600000
    const int NB = (N + BSZ - 1) >> BSH;  // 196

    char* ws = (char*)d_ws;
    size_t off = 0;
    auto bump = [&](size_t bytes) {
        char* p = ws + off;
        off += (bytes + 255) & ~(size_t)255;
        return p;
    };
    int* gCursor     = (int*)bump((size_t)NBMAX * 4);            // memset to 0
    float* norm      = (float*)bump((size_t)N * 4);
    int2* rsdeg      = (int2*)bump((size_t)N * 8);
    unsigned* tmp    = (unsigned*)bump((size_t)NB * LCAP * 4);   // 12.85 MB
    int* csr         = (int*)bump((size_t)NB * LCAP * 4);        // 12.85 MB
    unsigned* featb  = (unsigned*)bump((size_t)N * 64 * 4);      // bf16x2 rows
    unsigned* h1b    = (unsigned*)bump((size_t)N * 64 * 4);
    unsigned* h2b    = (unsigned*)bump((size_t)N * 64 * 4);
    ushort* Wb       = (ushort*)bump((size_t)D * 384 * 2);
    (void)ws_size;

    hipMemsetAsync(gCursor, 0, (size_t)NBMAX * 4, stream);

    const int nbin = (E + CH - 1) / CH;                // 391
    const int npre = (N * 64 + TPB - 1) / TPB;         // 25000
    const int nwcv = (D * 384 / 4 + TPB - 1) / TPB;    // 48
    mega_kernel<<<nbin + npre + nwcv, TPB, 0, stream>>>(
        src, dst, gCursor, tmp, feat, featb, W, Wb, E, N, nbin, npre);

    bucket_csr_kernel<<<NB, TPB, 0, stream>>>(tmp, gCursor, rsdeg, norm, csr, N);

    const int spmm_blocks = (N * 64 + TPB - 1) / TPB;  // 1 wave per node
    spmm_kernel<<<spmm_blocks, TPB, 0, stream>>>(
        (const uint4*)featb, rsdeg, csr, norm, h1b, N);
    spmm_kernel<<<spmm_blocks, TPB, 0, stream>>>(
        (const uint4*)h1b, rsdeg, csr, norm, h2b, N);

    const int ntiles = (N + 15) / 16;                  // 6250
    gemm_mfma_kernel<<<GEMM_GRID, TPB, 0, stream>>>(
        (const ushort*)featb, (const ushort*)h1b, (const ushort*)h2b,
        Wb, bias, out, N, ntiles);
}